// Round 1
// baseline (606.759 us; speedup 1.0000x reference)
//
#include <hip/hip_runtime.h>
#include <math.h>

#define BN_TOTAL 8192
#define D_MODEL  256
#define HEADS    8
#define DH       32
#define SEQ      2048

// ============================ GEMM (fp32) ============================
// C[M,N] = post( A[M,K] @ W[K,N] ), 64x64 block tile, 4x4 micro tile.
// post order: +bias -> relu -> +res ; optional accumulate into C.
template<int ACT, bool BIAS, bool RES, bool ACC>
__global__ __launch_bounds__(256) void gemm_f32(
    const float* __restrict__ A, int lda,
    const float* __restrict__ W, int ldw,
    const float* __restrict__ bias,
    const float* __restrict__ res,
    float* __restrict__ C, int ldc,
    int M, int N, int K)
{
    __shared__ float As[16][68];   // [k][m], padded
    __shared__ float Ws[16][68];   // [k][n], padded
    const int tid = threadIdx.x;
    const int tx = tid & 15, ty = tid >> 4;
    const int m0 = blockIdx.y * 64, n0 = blockIdx.x * 64;

    const int ar = tid >> 2;           // 0..63  (A row within tile)
    const int ak = (tid & 3) << 2;     // 0,4,8,12 (A k offset)
    const int wr = tid >> 4;           // 0..15  (W k row)
    const int wc = (tid & 15) << 2;    // 0..60  (W col offset)

    float acc[4][4] = {};

    for (int k0 = 0; k0 < K; k0 += 16) {
        float4 av = *(const float4*)&A[(size_t)(m0 + ar) * lda + k0 + ak];
        float4 wv = *(const float4*)&W[(size_t)(k0 + wr) * ldw + n0 + wc];
        As[ak + 0][ar] = av.x;
        As[ak + 1][ar] = av.y;
        As[ak + 2][ar] = av.z;
        As[ak + 3][ar] = av.w;
        *(float4*)&Ws[wr][wc] = wv;
        __syncthreads();
        #pragma unroll
        for (int k = 0; k < 16; ++k) {
            float4 a4 = *(const float4*)&As[k][ty * 4];
            float4 w4 = *(const float4*)&Ws[k][tx * 4];
            float aa[4] = {a4.x, a4.y, a4.z, a4.w};
            float ww[4] = {w4.x, w4.y, w4.z, w4.w};
            #pragma unroll
            for (int i = 0; i < 4; ++i)
                #pragma unroll
                for (int j = 0; j < 4; ++j)
                    acc[i][j] = fmaf(aa[i], ww[j], acc[i][j]);
        }
        __syncthreads();
    }

    float4 bv = make_float4(0.f, 0.f, 0.f, 0.f);
    if (BIAS) bv = *(const float4*)&bias[n0 + tx * 4];
    #pragma unroll
    for (int i = 0; i < 4; ++i) {
        const int row = m0 + ty * 4 + i;
        float v0 = acc[i][0], v1 = acc[i][1], v2 = acc[i][2], v3 = acc[i][3];
        if (BIAS) { v0 += bv.x; v1 += bv.y; v2 += bv.z; v3 += bv.w; }
        if (ACT == 1) {
            v0 = fmaxf(v0, 0.f); v1 = fmaxf(v1, 0.f);
            v2 = fmaxf(v2, 0.f); v3 = fmaxf(v3, 0.f);
        }
        if (RES) {
            float4 r4 = *(const float4*)&res[(size_t)row * ldc + n0 + tx * 4];
            v0 += r4.x; v1 += r4.y; v2 += r4.z; v3 += r4.w;
        }
        float* cp = &C[(size_t)row * ldc + n0 + tx * 4];
        if (ACC) {
            float4 c4 = *(const float4*)cp;
            v0 += c4.x; v1 += c4.y; v2 += c4.z; v3 += c4.w;
        }
        float4 o4 = make_float4(v0, v1, v2, v3);
        *(float4*)cp = o4;
    }
}

// ============================ LayerNorm ============================
// one wave (64 lanes) per row of 256; 4 rows per 256-thread block
__global__ __launch_bounds__(256) void layernorm_k(
    const float* __restrict__ X, const float* __restrict__ g,
    const float* __restrict__ b, float* __restrict__ Y)
{
    const int wid  = threadIdx.x >> 6;
    const int lane = threadIdx.x & 63;
    const int row  = blockIdx.x * 4 + wid;
    const float* xr = X + (size_t)row * D_MODEL;
    float4 v = *(const float4*)&xr[lane * 4];
    float s  = v.x + v.y + v.z + v.w;
    float sq = v.x * v.x + v.y * v.y + v.z * v.z + v.w * v.w;
    #pragma unroll
    for (int off = 32; off >= 1; off >>= 1) {
        s  += __shfl_xor(s, off);
        sq += __shfl_xor(sq, off);
    }
    const float mean = s * (1.f / D_MODEL);
    const float var  = sq * (1.f / D_MODEL) - mean * mean;
    const float rstd = rsqrtf(var + 1e-5f);
    float4 gv = *(const float4*)&g[lane * 4];
    float4 bv = *(const float4*)&b[lane * 4];
    float4 o;
    o.x = (v.x - mean) * rstd * gv.x + bv.x;
    o.y = (v.y - mean) * rstd * gv.y + bv.y;
    o.z = (v.z - mean) * rstd * gv.z + bv.z;
    o.w = (v.w - mean) * rstd * gv.w + bv.w;
    *(float4*)&Y[(size_t)row * D_MODEL + lane * 4] = o;
}

// ============================ Attention ============================
// flash-style; block = (q-tile of 64 rows, head, batch); fp32
// O1 = Q + softmax(Q K^T * scale) @ V   (per head), written to [BN, D]
__global__ __launch_bounds__(256) void attn_k(
    const float* __restrict__ Qg, const float* __restrict__ Kg,
    const float* __restrict__ Vg, float* __restrict__ O)
{
    const int qt = blockIdx.x, h = blockIdx.y, b = blockIdx.z;
    const int tid  = threadIdx.x;
    const int row0 = b * SEQ + qt * 64;
    const int col0 = h * DH;

    __shared__ float Qt[DH][68];   // [d][r] transposed
    __shared__ float Kt[DH][68];   // [d][c] transposed
    __shared__ float Vs[64][36];   // [c][d]
    __shared__ float Ss[64][68];   // scores / probs
    __shared__ float mrow[64], lrow[64], crow[64];

    // load Q tile (transposed into LDS)
    #pragma unroll
    for (int t = 0; t < 2; ++t) {
        int l = tid + t * 256;               // 0..511
        int r = l >> 3, c4 = (l & 7) << 2;
        float4 v = *(const float4*)&Qg[(size_t)(row0 + r) * D_MODEL + col0 + c4];
        Qt[c4 + 0][r] = v.x; Qt[c4 + 1][r] = v.y;
        Qt[c4 + 2][r] = v.z; Qt[c4 + 3][r] = v.w;
    }
    if (tid < 64) { mrow[tid] = -INFINITY; lrow[tid] = 0.f; }

    const int tx = tid & 15, ty = tid >> 4;
    const int sr0 = ty * 4;        // rows owned (S and O)
    const int sc0 = tx * 4;        // cols owned (S)
    const int od0 = tx * 2;        // dims owned (O), 0..30
    float oacc[4][2] = {};
    const float scale = 0.17677669529663687f;  // 1/sqrt(32)

    for (int k0 = 0; k0 < SEQ; k0 += 64) {
        __syncthreads();   // prev PV done before K/V overwrite
        #pragma unroll
        for (int t = 0; t < 2; ++t) {
            int l = tid + t * 256;
            int r = l >> 3, c4 = (l & 7) << 2;
            float4 kv = *(const float4*)&Kg[(size_t)(b * SEQ + k0 + r) * D_MODEL + col0 + c4];
            Kt[c4 + 0][r] = kv.x; Kt[c4 + 1][r] = kv.y;
            Kt[c4 + 2][r] = kv.z; Kt[c4 + 3][r] = kv.w;
            float4 vv = *(const float4*)&Vg[(size_t)(b * SEQ + k0 + r) * D_MODEL + col0 + c4];
            *(float4*)&Vs[r][c4] = vv;
        }
        __syncthreads();

        // S tile = Q K^T
        float sacc[4][4] = {};
        #pragma unroll 8
        for (int d = 0; d < DH; ++d) {
            float4 qa = *(const float4*)&Qt[d][sr0];
            float4 kb = *(const float4*)&Kt[d][sc0];
            float aa[4] = {qa.x, qa.y, qa.z, qa.w};
            float bb[4] = {kb.x, kb.y, kb.z, kb.w};
            #pragma unroll
            for (int i = 0; i < 4; ++i)
                #pragma unroll
                for (int j = 0; j < 4; ++j)
                    sacc[i][j] = fmaf(aa[i], bb[j], sacc[i][j]);
        }
        #pragma unroll
        for (int i = 0; i < 4; ++i)
            #pragma unroll
            for (int j = 0; j < 4; ++j)
                Ss[sr0 + i][sc0 + j] = sacc[i][j] * scale;
        __syncthreads();

        // online softmax row update (1 thread per row)
        if (tid < 64) {
            float m = mrow[tid];
            float mx = m;
            for (int j = 0; j < 64; ++j) mx = fmaxf(mx, Ss[tid][j]);
            float corr = __expf(m - mx);   // first tile: exp(-inf)=0
            float sum = 0.f;
            for (int j = 0; j < 64; ++j) {
                float p = __expf(Ss[tid][j] - mx);
                Ss[tid][j] = p;
                sum += p;
            }
            mrow[tid] = mx;
            lrow[tid] = lrow[tid] * corr + sum;
            crow[tid] = corr;
        }
        __syncthreads();

        // PV accumulate
        #pragma unroll
        for (int i = 0; i < 4; ++i) {
            float c = crow[sr0 + i];
            oacc[i][0] *= c; oacc[i][1] *= c;
        }
        for (int j = 0; j < 64; ++j) {
            float v0 = Vs[j][od0], v1 = Vs[j][od0 + 1];
            #pragma unroll
            for (int i = 0; i < 4; ++i) {
                float p = Ss[sr0 + i][j];
                oacc[i][0] = fmaf(p, v0, oacc[i][0]);
                oacc[i][1] = fmaf(p, v1, oacc[i][1]);
            }
        }
    }

    // epilogue: O = Q + attn/l
    #pragma unroll
    for (int i = 0; i < 4; ++i) {
        const int r = sr0 + i;
        const float inv = 1.f / lrow[r];
        #pragma unroll
        for (int dd = 0; dd < 2; ++dd) {
            const int d = od0 + dd;
            O[(size_t)(row0 + r) * D_MODEL + col0 + d] = Qt[d][r] + oacc[i][dd] * inv;
        }
    }
}

// ============================ launch ============================
extern "C" void kernel_launch(void* const* d_in, const int* in_sizes, int n_in,
                              void* d_out, int out_size, void* d_ws, size_t ws_size,
                              hipStream_t stream)
{
    (void)in_sizes; (void)n_in; (void)out_size; (void)ws_size;
    const float* q  = (const float*)d_in[0];
    const float* x  = (const float*)d_in[1];
    const float* Wq = (const float*)d_in[2];
    const float* bq = (const float*)d_in[3];
    const float* Wk = (const float*)d_in[4];
    const float* bk = (const float*)d_in[5];
    const float* Wv = (const float*)d_in[6];
    const float* bv = (const float*)d_in[7];
    const float* Wo = (const float*)d_in[8];
    const float* bo = (const float*)d_in[9];
    const float* Wm = (const float*)d_in[10];
    const float* bm = (const float*)d_in[11];
    const float* We = (const float*)d_in[12];
    const float* be = (const float*)d_in[13];
    const float* g0 = (const float*)d_in[14];
    const float* b0 = (const float*)d_in[15];
    const float* g1 = (const float*)d_in[16];
    const float* b1 = (const float*)d_in[17];
    float* out = (float*)d_out;

    const size_t SZ = (size_t)BN_TOTAL * D_MODEL;  // 2M floats (8 MB)
    float* Qb = (float*)d_ws;     // Q         -> later O2n
    float* Kb = Qb + SZ;          // K         -> later O1n
    float* Vb = Kb + SZ;          // V         -> later O2
    float* T3 = Vb + SZ;          // O1        -> later Mc chunks

    dim3 gg(D_MODEL / 64, BN_TOTAL / 64);   // (4, 128)

    // Q/K/V projections
    gemm_f32<0, true, false, false><<<gg, 256, 0, stream>>>(q, 256, Wq, 256, bq, nullptr, Qb, 256, BN_TOTAL, 256, 256);
    gemm_f32<0, true, false, false><<<gg, 256, 0, stream>>>(x, 256, Wk, 256, bk, nullptr, Kb, 256, BN_TOTAL, 256, 256);
    gemm_f32<0, true, false, false><<<gg, 256, 0, stream>>>(x, 256, Wv, 256, bv, nullptr, Vb, 256, BN_TOTAL, 256, 256);

    // attention + Q residual -> T3 (=O1)
    attn_k<<<dim3(SEQ / 64, HEADS, 4), 256, 0, stream>>>(Qb, Kb, Vb, T3);

    // LN0: O1 -> Kb (=O1n)
    layernorm_k<<<BN_TOTAL / 4, 256, 0, stream>>>(T3, g0, b0, Kb);

    // O2 = O1n + relu(O1n @ Wo + bo) -> Vb
    gemm_f32<1, true, true, false><<<gg, 256, 0, stream>>>(Kb, 256, Wo, 256, bo, Kb, Vb, 256, BN_TOTAL, 256, 256);

    // LN1: O2 -> Qb (=O2n)
    layernorm_k<<<BN_TOTAL / 4, 256, 0, stream>>>(Vb, g1, b1, Qb);

    // MLP: out = relu(O2n @ Wm + bm) @ We + be + O2, chunked over F in 4x256
    for (int c = 0; c < 4; ++c) {
        // Mc = relu(O2n @ Wm[:, c*256:+256] + bm[c*256:+256]) -> T3
        gemm_f32<1, true, false, false><<<gg, 256, 0, stream>>>(
            Qb, 256, Wm + c * 256, 1024, bm + c * 256, nullptr, T3, 256, BN_TOTAL, 256, 256);
        if (c == 0) {
            // out = Mc @ We[0:256,:] + be + O2
            gemm_f32<0, true, true, false><<<gg, 256, 0, stream>>>(
                T3, 256, We + (size_t)c * 256 * 256, 256, be, Vb, out, 256, BN_TOTAL, 256, 256);
        } else {
            // out += Mc @ We[c*256:+256,:]
            gemm_f32<0, false, false, true><<<gg, 256, 0, stream>>>(
                T3, 256, We + (size_t)c * 256 * 256, 256, nullptr, nullptr, out, 256, BN_TOTAL, 256, 256);
        }
    }
}

// Round 2
// 150.508 us; speedup vs baseline: 4.0314x; 4.0314x over previous
//
#include <hip/hip_runtime.h>
#include <math.h>
#include <stdint.h>

#define SEQ 2048
#define NB 4
#define DMODEL 256
#define HEADS 8
#define DH 32
#define BN_TOTAL 8192

typedef __attribute__((ext_vector_type(8))) __bf16 bf16x8;
typedef __attribute__((ext_vector_type(4))) float f32x4;

__device__ __forceinline__ unsigned short f2b(float f) {
  union { float f; uint32_t u; } v; v.f = f;
  uint32_t r = (v.u + 0x7FFFu + ((v.u >> 16) & 1u)) >> 16;
  return (unsigned short)r;
}
__device__ __forceinline__ float b2f(unsigned short u) {
  union { uint32_t u; float f; } v; v.u = ((uint32_t)u) << 16;
  return v.f;
}
__device__ __forceinline__ uint32_t pk2(float a, float b) {
  return (uint32_t)f2b(a) | ((uint32_t)f2b(b) << 16);
}
__device__ __forceinline__ void glds16(const void* g, void* l) {
  __builtin_amdgcn_global_load_lds(
      (const __attribute__((address_space(1))) void*)g,
      (__attribute__((address_space(3))) void*)l, 16, 0, 0);
}
#define MFMA16(a, b, c) __builtin_amdgcn_mfma_f32_16x16x32_bf16(a, b, c, 0, 0, 0)

// ===================== convert fp32 -> bf16 (copy) =====================
__global__ __launch_bounds__(256) void cvt32to16(
    const float* __restrict__ in, unsigned short* __restrict__ out, int n8) {
  int i = blockIdx.x * 256 + threadIdx.x;
  if (i < n8) {
    float4 a = ((const float4*)in)[i * 2];
    float4 b = ((const float4*)in)[i * 2 + 1];
    uint4 o;
    o.x = pk2(a.x, a.y); o.y = pk2(a.z, a.w);
    o.z = pk2(b.x, b.y); o.w = pk2(b.z, b.w);
    ((uint4*)out)[i] = o;
  }
}

// ============== weight transpose + convert: in f32 [K][N] -> out bf16 [N][K] ==============
__global__ __launch_bounds__(256) void transpose_cvt(
    const float* __restrict__ in, unsigned short* __restrict__ out,
    int ldin, int ldout) {
  __shared__ float T[64][68];
  const int k0 = blockIdx.x * 64, n0 = blockIdx.y * 64;
  const int t = threadIdx.x;
  const int r = t >> 2, c16 = (t & 3) * 16;
  #pragma unroll
  for (int i = 0; i < 4; ++i) {
    float4 v = *(const float4*)&in[(size_t)(k0 + r) * ldin + n0 + c16 + i * 4];
    *(float4*)&T[r][c16 + i * 4] = v;
  }
  __syncthreads();
  const int n = t >> 2, k16 = (t & 3) * 16;
  uint4 o[1];
  uint32_t w[8];
  #pragma unroll
  for (int p = 0; p < 8; ++p)
    w[p] = pk2(T[k16 + 2 * p][n], T[k16 + 2 * p + 1][n]);
  uint4 o0; o0.x = w[0]; o0.y = w[1]; o0.z = w[2]; o0.w = w[3];
  uint4 o1; o1.x = w[4]; o1.y = w[5]; o1.z = w[6]; o1.w = w[7];
  (void)o;
  *(uint4*)&out[(size_t)(n0 + n) * ldout + k0 + k16] = o0;
  *(uint4*)&out[(size_t)(n0 + n) * ldout + k0 + k16 + 8] = o1;
}

__global__ void packbias(const float* __restrict__ bk, const float* __restrict__ bv,
                         float* __restrict__ out) {
  int i = blockIdx.x * 256 + threadIdx.x;
  out[i] = (i < 256) ? bk[i] : bv[i - 256];
}

// ===================== MFMA GEMM: C[M,N] = A[M,K] @ Bt[N,K]^T =====================
// tile 64x64, 4 waves (wave tile 32x32), BK=32.
// EPI: 0 bias->bf16 | 1 res+relu(bias)->bf16 | 2 relu(bias)->bf16 | 3 bias+res->f32
template <int EPI>
__global__ __launch_bounds__(256, 4) void gemm_mfma(
    const unsigned short* __restrict__ A, int lda,
    const unsigned short* __restrict__ Bt, int ldb,
    const float* __restrict__ bias,
    const unsigned short* __restrict__ res, int ldr,
    void* __restrict__ Cout, int ldc, int K) {
  __shared__ __align__(16) unsigned short As[64 * 32];
  __shared__ __align__(16) unsigned short Bs[64 * 32];
  const int tid = threadIdx.x;
  const int lane = tid & 63, wid = tid >> 6;
  const int m0 = blockIdx.x * 64, n0 = blockIdx.y * 64;
  const int q = lane & 15, g = lane >> 4;
  const int wr = (wid >> 1) * 32, wc = (wid & 1) * 32;

  const unsigned short* ga = A + (size_t)(m0 + (tid >> 2)) * lda + (tid & 3) * 8;
  const unsigned short* gb = Bt + (size_t)(n0 + (tid >> 2)) * ldb + (tid & 3) * 8;
  unsigned short* lA = &As[wid * 512];
  unsigned short* lB = &Bs[wid * 512];

  f32x4 acc[2][2];
  #pragma unroll
  for (int i = 0; i < 2; ++i)
    #pragma unroll
    for (int j = 0; j < 2; ++j) acc[i][j] = (f32x4){0.f, 0.f, 0.f, 0.f};

  for (int k0 = 0; k0 < K; k0 += 32) {
    __syncthreads();
    glds16(ga, lA); ga += 32;
    glds16(gb, lB); gb += 32;
    __syncthreads();
    bf16x8 af0 = *(const bf16x8*)&As[(wr + q) * 32 + g * 8];
    bf16x8 af1 = *(const bf16x8*)&As[(wr + 16 + q) * 32 + g * 8];
    bf16x8 bf0 = *(const bf16x8*)&Bs[(wc + q) * 32 + g * 8];
    bf16x8 bf1 = *(const bf16x8*)&Bs[(wc + 16 + q) * 32 + g * 8];
    acc[0][0] = MFMA16(af0, bf0, acc[0][0]);
    acc[0][1] = MFMA16(af0, bf1, acc[0][1]);
    acc[1][0] = MFMA16(af1, bf0, acc[1][0]);
    acc[1][1] = MFMA16(af1, bf1, acc[1][1]);
  }

  const int colb = n0 + wc + q;
  const float bias0 = bias[colb];
  const float bias1 = bias[colb + 16];
  #pragma unroll
  for (int mf = 0; mf < 2; ++mf)
    #pragma unroll
    for (int j = 0; j < 4; ++j) {
      const int row = m0 + wr + mf * 16 + 4 * g + j;
      #pragma unroll
      for (int nf = 0; nf < 2; ++nf) {
        float v = acc[mf][nf][j] + (nf ? bias1 : bias0);
        if (EPI == 1 || EPI == 2) v = fmaxf(v, 0.f);
        const int col = colb + nf * 16;
        if (EPI == 1 || EPI == 3) v += b2f(res[(size_t)row * ldr + col]);
        if (EPI == 3)
          ((float*)Cout)[(size_t)row * ldc + col] = v;
        else
          ((unsigned short*)Cout)[(size_t)row * ldc + col] = f2b(v);
      }
    }
}

// ===================== fused attention (bf16 MFMA, flash-style) =====================
// grid (32 qtiles, 8 heads, 4 batch); 256 thr = 4 waves; each wave owns 16 q-rows.
// computes O1 = Qproj + softmax(Q K^T / sqrt(dh)) @ V   per head.
__global__ __launch_bounds__(256, 3) void attn_mfma(
    const unsigned short* __restrict__ Qg,   // [8192][256]
    const unsigned short* __restrict__ KVg,  // [8192][512]: K cols 0..255, V cols 256..511
    unsigned short* __restrict__ O1) {       // [8192][256]
  __shared__ __align__(16) unsigned short Qs[64 * 32];
  __shared__ __align__(16) unsigned short Ks[64 * 32];
  __shared__ __align__(16) unsigned short VT[32 * 72];  // [d][k], stride 72
  const int tid = threadIdx.x;
  const int lane = tid & 63, wid = tid >> 6;
  const int qt = blockIdx.x, h = blockIdx.y, b = blockIdx.z;
  const int row0 = b * SEQ + qt * 64;
  const int q = lane & 15, g = lane >> 4;

  glds16(Qg + (size_t)(row0 + (tid >> 2)) * 256 + h * 32 + (tid & 3) * 8,
         &Qs[wid * 512]);

  const int vd = tid & 31;
  const int vk0 = (tid >> 5) * 4;
  __syncthreads();
  const bf16x8 qf = *(const bf16x8*)&Qs[(wid * 16 + q) * 32 + g * 8];

  f32x4 ot0 = (f32x4){0.f, 0.f, 0.f, 0.f};
  f32x4 ot1 = (f32x4){0.f, 0.f, 0.f, 0.f};
  float mrun = -INFINITY, lrun = 0.f;
  const float SCL = 0.17677669529663687f * 1.4426950408889634f;  // 1/sqrt(32)*log2(e)
  const f32x4 zero = (f32x4){0.f, 0.f, 0.f, 0.f};

  const int s1 = (((g * 2) & 3) << 4) | q;
  const int s2 = (((g * 2 + 1) & 3) << 4) | q;
  const bool hi = (g >= 2);

  for (int kt = 0; kt < SEQ; kt += 64) {
    __syncthreads();
    glds16(KVg + (size_t)(b * SEQ + kt + (tid >> 2)) * 512 + h * 32 + (tid & 3) * 8,
           &Ks[wid * 512]);
    {
      const unsigned short* vsrc =
          KVg + (size_t)(b * SEQ + kt) * 512 + 256 + h * 32 + vd;
      unsigned short a0 = vsrc[(size_t)(vk0 + 0) * 512];
      unsigned short a1 = vsrc[(size_t)(vk0 + 1) * 512];
      unsigned short a2 = vsrc[(size_t)(vk0 + 2) * 512];
      unsigned short a3 = vsrc[(size_t)(vk0 + 3) * 512];
      unsigned short c0 = vsrc[(size_t)(vk0 + 32) * 512];
      unsigned short c1 = vsrc[(size_t)(vk0 + 33) * 512];
      unsigned short c2 = vsrc[(size_t)(vk0 + 34) * 512];
      unsigned short c3 = vsrc[(size_t)(vk0 + 35) * 512];
      uint2 w0, w1;
      w0.x = (uint32_t)a0 | ((uint32_t)a1 << 16);
      w0.y = (uint32_t)a2 | ((uint32_t)a3 << 16);
      w1.x = (uint32_t)c0 | ((uint32_t)c1 << 16);
      w1.y = (uint32_t)c2 | ((uint32_t)c3 << 16);
      *(uint2*)&VT[vd * 72 + vk0] = w0;
      *(uint2*)&VT[vd * 72 + vk0 + 32] = w1;
    }
    __syncthreads();

    // S^T tile: 4 fragments, rows k = f*16 + 4g + j, col q-row = wave's 16 q's
    f32x4 s0, s1v, s2v, s3;
    {
      bf16x8 kf0 = *(const bf16x8*)&Ks[(0 * 16 + q) * 32 + g * 8];
      bf16x8 kf1 = *(const bf16x8*)&Ks[(1 * 16 + q) * 32 + g * 8];
      bf16x8 kf2 = *(const bf16x8*)&Ks[(2 * 16 + q) * 32 + g * 8];
      bf16x8 kf3 = *(const bf16x8*)&Ks[(3 * 16 + q) * 32 + g * 8];
      s0 = MFMA16(kf0, qf, zero);
      s1v = MFMA16(kf1, qf, zero);
      s2v = MFMA16(kf2, qf, zero);
      s3 = MFMA16(kf3, qf, zero);
    }
    float tv[16];
    #pragma unroll
    for (int j = 0; j < 4; ++j) {
      tv[0 + j] = s0[j] * SCL;
      tv[4 + j] = s1v[j] * SCL;
      tv[8 + j] = s2v[j] * SCL;
      tv[12 + j] = s3[j] * SCL;
    }
    float tmax = tv[0];
    #pragma unroll
    for (int i = 1; i < 16; ++i) tmax = fmaxf(tmax, tv[i]);
    tmax = fmaxf(tmax, __shfl_xor(tmax, 16));
    tmax = fmaxf(tmax, __shfl_xor(tmax, 32));
    const float mnew = fmaxf(mrun, tmax);
    const float corr = __builtin_amdgcn_exp2f(mrun - mnew);
    float p[16];
    float rsum = 0.f;
    #pragma unroll
    for (int i = 0; i < 16; ++i) {
      p[i] = __builtin_amdgcn_exp2f(tv[i] - mnew);
      rsum += p[i];
    }
    rsum += __shfl_xor(rsum, 16);
    rsum += __shfl_xor(rsum, 32);
    lrun = lrun * corr + rsum;
    mrun = mnew;
    ot0 *= corr;
    ot1 *= corr;

    // pack P^T bundles: bund[f] covers k = f*16 + 4g + {0..3} for this lane's q
    uint32_t bund[4][2];
    #pragma unroll
    for (int f = 0; f < 4; ++f) {
      bund[f][0] = pk2(p[f * 4 + 0], p[f * 4 + 1]);
      bund[f][1] = pk2(p[f * 4 + 2], p[f * 4 + 3]);
    }
    // PV: O^T += V^T @ P^T, kd-chunks of 32
    #pragma unroll
    for (int c = 0; c < 2; ++c) {
      uint32_t x0 = (uint32_t)__shfl((int)bund[2 * c][0], s1);
      uint32_t x1 = (uint32_t)__shfl((int)bund[2 * c][1], s1);
      uint32_t y0 = (uint32_t)__shfl((int)bund[2 * c + 1][0], s1);
      uint32_t y1 = (uint32_t)__shfl((int)bund[2 * c + 1][1], s1);
      uint32_t x2 = (uint32_t)__shfl((int)bund[2 * c][0], s2);
      uint32_t x3 = (uint32_t)__shfl((int)bund[2 * c][1], s2);
      uint32_t y2 = (uint32_t)__shfl((int)bund[2 * c + 1][0], s2);
      uint32_t y3 = (uint32_t)__shfl((int)bund[2 * c + 1][1], s2);
      union { uint32_t u[4]; bf16x8 v; } pu;
      pu.u[0] = hi ? y0 : x0;
      pu.u[1] = hi ? y1 : x1;
      pu.u[2] = hi ? y2 : x2;
      pu.u[3] = hi ? y3 : x3;
      bf16x8 pb = pu.v;
      bf16x8 vf0 = *(const bf16x8*)&VT[(0 * 16 + q) * 72 + c * 32 + g * 8];
      bf16x8 vf1 = *(const bf16x8*)&VT[(1 * 16 + q) * 72 + c * 32 + g * 8];
      ot0 = MFMA16(vf0, pb, ot0);
      ot1 = MFMA16(vf1, pb, ot1);
    }
  }

  // epilogue: O1[q-row][d] = Q + O^T/l
  const float inv = 1.0f / lrun;
  const int orow = row0 + wid * 16 + q;
  #pragma unroll
  for (int dg = 0; dg < 2; ++dg) {
    const unsigned short* qres = &Qs[(wid * 16 + q) * 32 + dg * 16 + g * 4];
    f32x4 o = dg ? ot1 : ot0;
    float r0 = b2f(qres[0]) + o[0] * inv;
    float r1 = b2f(qres[1]) + o[1] * inv;
    float r2 = b2f(qres[2]) + o[2] * inv;
    float r3 = b2f(qres[3]) + o[3] * inv;
    uint2 w;
    w.x = pk2(r0, r1);
    w.y = pk2(r2, r3);
    *(uint2*)&O1[(size_t)orow * 256 + h * 32 + dg * 16 + g * 4] = w;
  }
}

// ===================== LayerNorm (bf16 in/out) =====================
__global__ __launch_bounds__(256) void ln_k(
    const unsigned short* __restrict__ X, const float* __restrict__ gw,
    const float* __restrict__ bw, unsigned short* __restrict__ Y) {
  const int wid = threadIdx.x >> 6, lane = threadIdx.x & 63;
  const int row = blockIdx.x * 4 + wid;
  ushort4 xv = *(const ushort4*)(X + (size_t)row * 256 + lane * 4);
  float x0 = b2f(xv.x), x1 = b2f(xv.y), x2 = b2f(xv.z), x3 = b2f(xv.w);
  float s = x0 + x1 + x2 + x3;
  float sq = x0 * x0 + x1 * x1 + x2 * x2 + x3 * x3;
  #pragma unroll
  for (int off = 32; off >= 1; off >>= 1) {
    s += __shfl_xor(s, off);
    sq += __shfl_xor(sq, off);
  }
  const float mean = s * (1.f / 256.f);
  const float var = sq * (1.f / 256.f) - mean * mean;
  const float rstd = rsqrtf(var + 1e-5f);
  float4 gv = *(const float4*)&gw[lane * 4];
  float4 bv = *(const float4*)&bw[lane * 4];
  ushort4 o;
  o.x = f2b((x0 - mean) * rstd * gv.x + bv.x);
  o.y = f2b((x1 - mean) * rstd * gv.y + bv.y);
  o.z = f2b((x2 - mean) * rstd * gv.z + bv.z);
  o.w = f2b((x3 - mean) * rstd * gv.w + bv.w);
  *(ushort4*)(Y + (size_t)row * 256 + lane * 4) = o;
}

// ===================== launch =====================
extern "C" void kernel_launch(void* const* d_in, const int* in_sizes, int n_in,
                              void* d_out, int out_size, void* d_ws, size_t ws_size,
                              hipStream_t stream) {
  (void)in_sizes; (void)n_in; (void)out_size; (void)ws_size;
  const float* q = (const float*)d_in[0];
  const float* x = (const float*)d_in[1];
  const float* Wq = (const float*)d_in[2];
  const float* bq = (const float*)d_in[3];
  const float* Wk = (const float*)d_in[4];
  const float* bk = (const float*)d_in[5];
  const float* Wv = (const float*)d_in[6];
  const float* bv = (const float*)d_in[7];
  const float* Wo = (const float*)d_in[8];
  const float* bo = (const float*)d_in[9];
  const float* Wm = (const float*)d_in[10];
  const float* bm = (const float*)d_in[11];
  const float* We = (const float*)d_in[12];
  const float* be = (const float*)d_in[13];
  const float* g0 = (const float*)d_in[14];
  const float* b0 = (const float*)d_in[15];
  const float* g1 = (const float*)d_in[16];
  const float* b1 = (const float*)d_in[17];
  float* out = (float*)d_out;

  uint8_t* ws = (uint8_t*)d_ws;
  unsigned short* WqT = (unsigned short*)(ws + 0);
  unsigned short* WkvT = (unsigned short*)(ws + 131072);
  unsigned short* WoT = (unsigned short*)(ws + 393216);
  unsigned short* WmT = (unsigned short*)(ws + 524288);
  unsigned short* WeT = (unsigned short*)(ws + 1048576);
  float* bkv = (float*)(ws + 1572864);
  unsigned short* Mb = (unsigned short*)(ws + 2097152);           // 16 MB region
  unsigned short* Qb = (unsigned short*)(ws + 2097152);           // alias (dead before Mb)
  unsigned short* KVb = (unsigned short*)(ws + 2097152 + 4194304);
  unsigned short* O1 = (unsigned short*)(ws + 2097152 + 12582912);
  unsigned short* bufA = (unsigned short*)(ws + 18874368);        // qh -> O1n
  unsigned short* bufB = (unsigned short*)(ws + 23068672);        // xh -> O2n
  unsigned short* bufC = (unsigned short*)(ws + 27262976);        // O2

  // conversions
  cvt32to16<<<1024, 256, 0, stream>>>(q, bufA, 262144);
  cvt32to16<<<1024, 256, 0, stream>>>(x, bufB, 262144);
  transpose_cvt<<<dim3(4, 4), 256, 0, stream>>>(Wq, WqT, 256, 256);
  transpose_cvt<<<dim3(4, 4), 256, 0, stream>>>(Wk, WkvT, 256, 256);
  transpose_cvt<<<dim3(4, 4), 256, 0, stream>>>(Wv, WkvT + 65536, 256, 256);
  transpose_cvt<<<dim3(4, 4), 256, 0, stream>>>(Wo, WoT, 256, 256);
  transpose_cvt<<<dim3(4, 16), 256, 0, stream>>>(Wm, WmT, 1024, 256);
  transpose_cvt<<<dim3(16, 4), 256, 0, stream>>>(We, WeT, 256, 1024);
  packbias<<<2, 256, 0, stream>>>(bk, bv, bkv);

  // projections
  gemm_mfma<0><<<dim3(128, 4), 256, 0, stream>>>(bufA, 256, WqT, 256, bq, nullptr, 0, Qb, 256, 256);
  gemm_mfma<0><<<dim3(128, 8), 256, 0, stream>>>(bufB, 256, WkvT, 256, bkv, nullptr, 0, KVb, 512, 256);

  // attention + Q residual
  attn_mfma<<<dim3(32, 8, 4), 256, 0, stream>>>(Qb, KVb, O1);

  // LN0 -> O1n (bufA)
  ln_k<<<2048, 256, 0, stream>>>(O1, g0, b0, bufA);
  // O2 = O1n + relu(O1n@Wo + bo) -> bufC
  gemm_mfma<1><<<dim3(128, 4), 256, 0, stream>>>(bufA, 256, WoT, 256, bo, bufA, 256, bufC, 256, 256);
  // LN1 -> O2n (bufB)
  ln_k<<<2048, 256, 0, stream>>>(bufC, g1, b1, bufB);
  // M = relu(O2n@Wm + bm) -> Mb
  gemm_mfma<2><<<dim3(128, 16), 256, 0, stream>>>(bufB, 256, WmT, 256, bm, nullptr, 0, Mb, 1024, 256);
  // out = M@We + be + O2 -> d_out (fp32)
  gemm_mfma<3><<<dim3(128, 4), 256, 0, stream>>>(Mb, 1024, WeT, 1024, be, bufC, 256, out, 256, 1024);
}